// Round 8
// baseline (245.069 us; speedup 1.0000x reference)
//
#include <hip/hip_runtime.h>
#include <hip/hip_bf16.h>

#define N_NODES 50000
#define N_EDGES 800000
#define IN_FEAT 256
#define UNITS   128
#define SUB     16                      // sub-counters per node (atomic spread)
#define NSEG    (N_NODES * SUB)         // 800000 counters, strided layout

typedef unsigned short ushort_t;
typedef __bf16 bf16x8 __attribute__((ext_vector_type(8)));
typedef float  f32x4  __attribute__((ext_vector_type(4)));
typedef unsigned short ushort8 __attribute__((ext_vector_type(8)));

__device__ __forceinline__ ushort_t f2bf(float f) {
    unsigned u = __float_as_uint(f);
    u += 0x7fff + ((u >> 16) & 1);      // round-to-nearest-even
    return (ushort_t)(u >> 16);
}

// ---------------------------------------------------------------------------
// K0: Wt[n][k] = bf16(W[k][n]) AND zero counts[NSEG]  (R6-proven pattern).
// ---------------------------------------------------------------------------
__global__ __launch_bounds__(256) void prep_zero(const float* __restrict__ W,
                                                 ushort_t* __restrict__ Wt,
                                                 int* __restrict__ counts) {
    int i = blockIdx.x * 256 + threadIdx.x;
    if (i < UNITS * IN_FEAT) {
        int n = i >> 8;
        int k = i & 255;
        Wt[i] = f2bf(W[(size_t)k * UNITS + n]);
    }
    if (i < NSEG) counts[i] = 0;
}

// ---------------------------------------------------------------------------
// K1: h(bf16) = A @ W via MFMA 16x16x32 bf16  (R5/R6-proven, unmodified).
// ---------------------------------------------------------------------------
__global__ __launch_bounds__(256) void gemm_mfma(const float* __restrict__ A,
                                                 const ushort_t* __restrict__ Wt,
                                                 ushort_t* __restrict__ Hb, int M) {
    __shared__ __align__(16) ushort_t As[64 * 40];    // 5 KB
    __shared__ __align__(16) ushort_t Bs[128 * 40];   // 10 KB
    const int tid  = threadIdx.x;
    const int lane = tid & 63;
    const int wv   = tid >> 6;
    const int wy   = wv >> 1;
    const int wx   = wv & 1;
    const int row0 = blockIdx.x * 64;
    const int quad = lane >> 4;
    const int cl   = lane & 15;

    f32x4 acc[2][4] = {};

    const int ar = tid >> 2, aq = tid & 3;
    const int gr = min(row0 + ar, M - 1);
    const float*    aptr   = A + (size_t)gr * IN_FEAT + aq * 8;
    ushort_t*       as_dst = As + ar * 40 + aq * 8;
    const int br = tid >> 1, bh = tid & 1;
    const ushort_t* wptr   = Wt + br * IN_FEAT + bh * 16;
    ushort_t*       bs_dst = Bs + br * 40 + bh * 16;

    for (int kc = 0; kc < IN_FEAT; kc += 32) {
        float4 f0 = *(const float4*)(aptr + kc);
        float4 f1 = *(const float4*)(aptr + kc + 4);
        ushort8 w0 = *(const ushort8*)(wptr + kc);
        ushort8 w1 = *(const ushort8*)(wptr + kc + 8);
        ushort8 u;
        u[0] = f2bf(f0.x); u[1] = f2bf(f0.y); u[2] = f2bf(f0.z); u[3] = f2bf(f0.w);
        u[4] = f2bf(f1.x); u[5] = f2bf(f1.y); u[6] = f2bf(f1.z); u[7] = f2bf(f1.w);
        __syncthreads();
        *(ushort8*)as_dst = u;
        *(ushort8*)bs_dst        = w0;
        *(ushort8*)(bs_dst + 8)  = w1;
        __syncthreads();

        bf16x8 af[2], bff[4];
#pragma unroll
        for (int mi = 0; mi < 2; ++mi)
            af[mi] = *(const bf16x8*)(As + (wy * 32 + mi * 16 + cl) * 40 + quad * 8);
#pragma unroll
        for (int ni = 0; ni < 4; ++ni)
            bff[ni] = *(const bf16x8*)(Bs + (wx * 64 + ni * 16 + cl) * 40 + quad * 8);
#pragma unroll
        for (int mi = 0; mi < 2; ++mi)
#pragma unroll
            for (int ni = 0; ni < 4; ++ni)
                acc[mi][ni] = __builtin_amdgcn_mfma_f32_16x16x32_bf16(
                    af[mi], bff[ni], acc[mi][ni], 0, 0, 0);
    }

#pragma unroll
    for (int mi = 0; mi < 2; ++mi) {
#pragma unroll
        for (int ni = 0; ni < 4; ++ni) {
            int col = wx * 64 + ni * 16 + cl;
#pragma unroll
            for (int r = 0; r < 4; ++r) {
                int row = row0 + wy * 32 + mi * 16 + quad * 4 + r;
                if (row < M)
                    Hb[(size_t)row * UNITS + col] = f2bf(acc[mi][ni][r]);
            }
        }
    }
}

// ---------------------------------------------------------------------------
// K1b: per-node attention logits from bf16 h (R5-proven, unmodified).
// ---------------------------------------------------------------------------
__global__ __launch_bounds__(256) void attn_dots(const ushort_t* __restrict__ Hb,
                                                 const float* __restrict__ ka,
                                                 float* __restrict__ a_tgt,
                                                 float* __restrict__ a_src, int M) {
    int wid  = (int)((blockIdx.x * 256 + threadIdx.x) >> 6);
    int lane = threadIdx.x & 63;
    if (wid >= M) return;
    unsigned u = *(const unsigned*)(Hb + (size_t)wid * UNITS + lane * 2);
    float h0 = __uint_as_float(u << 16);
    float h1 = __uint_as_float(u & 0xffff0000u);
    float2 kt = *(const float2*)(ka + lane * 2);
    float2 ks = *(const float2*)(ka + UNITS + lane * 2);
    float pt = h0 * kt.x + h1 * kt.y;
    float ps = h0 * ks.x + h1 * ks.y;
#pragma unroll
    for (int off = 32; off > 0; off >>= 1) {
        pt += __shfl_down(pt, off);
        ps += __shfl_down(ps, off);
    }
    if (lane == 0) { a_tgt[wid] = pt; a_src[wid] = ps; }
}

__device__ __forceinline__ float edge_score(float at, float as) {
    float s = at + as;
    s = s > 0.f ? s : 0.2f * s;          // leaky_relu
    s = fminf(fmaxf(s, -2.f), 2.f);      // clip
    return __expf(s);
}

// ---------------------------------------------------------------------------
// K2: rank within sub-counter (e&15)*N_NODES + tgt. Strided layout: same
// node's 16 sub-counters live on 16 DIFFERENT cache lines -> both line- and
// address-level atomic contention drop 16x vs single counter per node.
// ---------------------------------------------------------------------------
__global__ __launch_bounds__(256) void edge_rank(const int* __restrict__ edges,
                                                 int* __restrict__ counts,
                                                 int* __restrict__ rank_, int E) {
    int e = blockIdx.x * 256 + threadIdx.x;
    if (e >= E) return;
    int2 ts = ((const int2*)edges)[e];   // (tgt, src)
    rank_[e] = atomicAdd(&counts[(e & (SUB - 1)) * N_NODES + ts.x], 1);
}

// ---------------------------------------------------------------------------
// K2b: per-node prefix over its 16 sub-counters (strided planes, coalesced).
// sub_base[s*N + n] = sum of counts[s'*N + n] for s' < s; node_total[n] = sum.
// One thread per node; trivially independent.
// ---------------------------------------------------------------------------
__global__ __launch_bounds__(256) void node_prefix(const int* __restrict__ counts,
                                                   int* __restrict__ sub_base,
                                                   int* __restrict__ node_total,
                                                   int M) {
    int n = blockIdx.x * 256 + threadIdx.x;
    if (n >= M) return;
    int run = 0;
#pragma unroll
    for (int s = 0; s < SUB; ++s) {
        int c = counts[s * N_NODES + n];
        sub_base[s * N_NODES + n] = run;
        run += c;
    }
    node_total[n] = run;
}

// ---------------------------------------------------------------------------
// K3: single-block chunked scan over node_total[0..M) -> node_off[0..M]
// (R6 fusedB block-0 code, proven; 256 thr x 32 elems, 7 chunks).
// OOB int4 reads land in our own ws (node_off region) and are masked.
// ---------------------------------------------------------------------------
__global__ __launch_bounds__(256) void scan_offsets(const int* __restrict__ vals,
                                                    int* __restrict__ node_off, int M) {
    __shared__ int wsum[4];
    __shared__ int total_sh;
    const int tid = threadIdx.x;
    const int lane = tid & 63, wv = tid >> 6;
    const int CH = 256 * 32;
    const int nch = (M + CH - 1) / CH;
    int base = 0;
    for (int ch = 0; ch < nch; ++ch) {
        int i0 = ch * CH + tid * 32;
        int a[32];
#pragma unroll
        for (int j = 0; j < 8; ++j) {
            int4 v = *(const int4*)(vals + i0 + j * 4);
            a[j * 4 + 0] = v.x; a[j * 4 + 1] = v.y;
            a[j * 4 + 2] = v.z; a[j * 4 + 3] = v.w;
        }
        int run = 0;
#pragma unroll
        for (int k = 0; k < 32; ++k) {
            int val = (i0 + k < M) ? a[k] : 0;
            a[k] = run;
            run += val;
        }
        int incl = run;
#pragma unroll
        for (int off = 1; off < 64; off <<= 1) {
            int t = __shfl_up(incl, off);
            if (lane >= off) incl += t;
        }
        if (lane == 63) wsum[wv] = incl;
        __syncthreads();
        if (tid == 0) {
            int r = 0;
#pragma unroll
            for (int i = 0; i < 4; ++i) { int x = wsum[i]; wsum[i] = r; r += x; }
            total_sh = r;
        }
        __syncthreads();
        int tb = base + wsum[wv] + (incl - run);
#pragma unroll
        for (int k = 0; k < 32; ++k)
            if (i0 + k < M) node_off[i0 + k] = tb + a[k];
        base += total_sh;
        __syncthreads();
    }
    if (tid == 0) node_off[M] = base;
}

// ---------------------------------------------------------------------------
// K4: atomic-free CSR scatter (R5-proven + sub_base term).
// ---------------------------------------------------------------------------
__global__ __launch_bounds__(256) void build_csr(const int* __restrict__ edges,
                                                 const int* __restrict__ rank_,
                                                 const float* __restrict__ at,
                                                 const float* __restrict__ as,
                                                 const int* __restrict__ node_off,
                                                 const int* __restrict__ sub_base,
                                                 int2* __restrict__ csr, int E) {
    int e = blockIdx.x * 256 + threadIdx.x;
    if (e >= E) return;
    int2 ts = ((const int2*)edges)[e];
    float sc = edge_score(at[ts.x], as[ts.y]);
    int pos = node_off[ts.x] + sub_base[(e & (SUB - 1)) * N_NODES + ts.x] + rank_[e];
    csr[pos] = make_int2(ts.y, __float_as_int(sc));
}

// ---------------------------------------------------------------------------
// K5: one wave per target node; 4 edge-slots x 16 feature-lanes (R5-proven).
// ---------------------------------------------------------------------------
__global__ __launch_bounds__(256) void aggregate(const ushort_t* __restrict__ Hb,
                                                 const int* __restrict__ node_off,
                                                 const int2* __restrict__ csr,
                                                 float* __restrict__ out, int M) {
    int wid  = (int)((blockIdx.x * 256 + threadIdx.x) >> 6);
    int lane = threadIdx.x & 63;
    if (wid >= M) return;
    const int g = lane >> 4;
    const int c = lane & 15;
    int beg = node_off[wid];
    int end = node_off[wid + 1];

    float acc[8] = {};
    float wacc = 0.f;

    for (int base = beg; base < end; base += 64) {
        int cd = min(64, end - base);
        int   s_v = 0;
        float w_v = 0.f;
        if (lane < cd) {
            int2 sw = csr[base + lane];
            s_v = sw.x;
            w_v = __int_as_float(sw.y);
        }
        wacc += w_v;
        int nstep = (cd + 3) >> 2;
#pragma unroll 4
        for (int t = 0; t < nstep; ++t) {
            int slot = t * 4 + g;
            int   src = __shfl(s_v, slot);
            float w   = __shfl(w_v, slot);
            uint4 u = *(const uint4*)(Hb + (size_t)src * UNITS + c * 8);
            acc[0] += w * __uint_as_float(u.x << 16);
            acc[1] += w * __uint_as_float(u.x & 0xffff0000u);
            acc[2] += w * __uint_as_float(u.y << 16);
            acc[3] += w * __uint_as_float(u.y & 0xffff0000u);
            acc[4] += w * __uint_as_float(u.z << 16);
            acc[5] += w * __uint_as_float(u.z & 0xffff0000u);
            acc[6] += w * __uint_as_float(u.w << 16);
            acc[7] += w * __uint_as_float(u.w & 0xffff0000u);
        }
    }

#pragma unroll
    for (int i = 0; i < 8; ++i) {
        acc[i] += __shfl_xor(acc[i], 16);
        acc[i] += __shfl_xor(acc[i], 32);
    }
#pragma unroll
    for (int off = 32; off > 0; off >>= 1) wacc += __shfl_xor(wacc, off);
    float scale = (end > beg) ? 1.0f / wacc : 0.0f;

    if (g == 0) {
        float4 o0 = make_float4(acc[0] * scale, acc[1] * scale,
                                acc[2] * scale, acc[3] * scale);
        float4 o1 = make_float4(acc[4] * scale, acc[5] * scale,
                                acc[6] * scale, acc[7] * scale);
        float* dst = out + (size_t)wid * UNITS + c * 8;
        *(float4*)dst       = o0;
        *(float4*)(dst + 4) = o1;
    }
}

// ---------------------------------------------------------------------------
extern "C" void kernel_launch(void* const* d_in, const int* in_sizes, int n_in,
                              void* d_out, int out_size, void* d_ws, size_t ws_size,
                              hipStream_t stream) {
    const float* node_states = (const float*)d_in[0];
    const int*   edges       = (const int*)d_in[1];   // int32 pairs (tgt,src)
    const float* W           = (const float*)d_in[2];
    const float* ka          = (const float*)d_in[3];
    float*       out         = (float*)d_out;

    const int M = N_NODES, E = N_EDGES;

    // workspace layout (ints; all large arrays 16B-aligned; no trailing
    // backslashes in comments!)
    ushort_t* hb      = (ushort_t*)d_ws;                  // 3,200,000 ints
    float*    a_tgt   = (float*)(hb + (size_t)M * UNITS); // 50,000
    float*    a_src   = a_tgt + M;                        // 50,000
    int*      counts  = (int*)(a_src + M);                // 800,000 (strided SUB)
    int*      sub_base= counts + NSEG;                    // 800,000
    int*      node_tot= sub_base + NSEG;                  // 57,600 (pad: scan OOB int4 reads)
    int*      node_off= node_tot + 57600;                 // 50,002
    int*      rank_   = node_off + M + 2;                 // 800,000
    int2*     csr     = (int2*)(rank_ + E);               // 800,000 int2
    // total ~29.6 MB. Wt (64KB bf16) aliases csr: used only by
    // prep_zero/gemm_mfma which finish before build_csr writes csr.
    ushort_t* wt      = (ushort_t*)csr;

    prep_zero   <<<(NSEG + 255) / 256, 256, 0, stream>>>(W, wt, counts);
    gemm_mfma   <<<(M + 63) / 64, 256, 0, stream>>>(node_states, wt, hb, M);
    attn_dots   <<<(M * 64 + 255) / 256, 256, 0, stream>>>(hb, ka, a_tgt, a_src, M);
    edge_rank   <<<(E + 255) / 256, 256, 0, stream>>>(edges, counts, rank_, E);
    node_prefix <<<(M + 255) / 256, 256, 0, stream>>>(counts, sub_base, node_tot, M);
    scan_offsets<<<1, 256, 0, stream>>>(node_tot, node_off, M);
    build_csr   <<<(E + 255) / 256, 256, 0, stream>>>(edges, rank_, a_tgt, a_src,
                                                      node_off, sub_base, csr, E);
    aggregate   <<<(M * 64 + 255) / 256, 256, 0, stream>>>(hb, node_off, csr, out, M);
}